// Round 8
// baseline (2218.013 us; speedup 1.0000x reference)
//
#include <hip/hip_runtime.h>

#define N_PTS 8192
#define NSAMP 1024
#define NGRP  32

// DPP max step: invalid lanes keep 'old' (=r), identity for max.
#define DPP_MAXSTEP(r, ctrl)                                                  \
  r = fmaxf(r, __int_as_float(__builtin_amdgcn_update_dpp(                    \
          __float_as_int(r), __float_as_int(r), (ctrl), 0xf, 0xf, false)))

// ---------------------------------------------------------------------------
// Kernel 1: farthest point sampling. One block of 512 threads (8 waves) per
// batch; each thread owns 16 consecutive points in registers.
// Distance rounding matches XLA:CPU's scan-compiled contracted reduce:
//   d = fma(dz,dz, fma(dy,dy, dx*dx))          (bit-exact, DO NOT TOUCH)
// argmax ties -> lowest index.
//
// R7 finding: kernel is SERIAL-CHAIN-bound (VGPR 44->88 changed nothing).
// This round removes the dependent global centroid load (~300-400cy, L2)
// from the chain: each wave pre-selects its candidate's coords from regs
// (independent of the DPP chain -> hidden), the winning lane publishes
// (v, idx, x, y, z) to LDS, and the post-barrier scan yields the next
// centroid directly. Zero global loads inside the loop.
// ---------------------------------------------------------------------------
__global__
__attribute__((amdgpu_flat_work_group_size(512, 512)))
__attribute__((amdgpu_waves_per_eu(2, 2)))
void fps_kernel(
    const float* __restrict__ xyz, float* __restrict__ out_sampled)
{
  #pragma clang fp contract(off)
  const int b = blockIdx.x;
  const int t = threadIdx.x;
  const float* bx = xyz + (size_t)b * N_PTS * 3;

  float px[16], py[16], pz[16], dist[16];
  {
    const float4* src = (const float4*)(bx + t * 48);
    float4 v0 = src[0], v1 = src[1], v2 = src[2];
    float4 v3 = src[3], v4 = src[4], v5 = src[5];
    float4 v6 = src[6], v7 = src[7], v8 = src[8];
    float4 v9 = src[9], v10 = src[10], v11 = src[11];
    px[ 0]=v0.x; py[ 0]=v0.y; pz[ 0]=v0.z;
    px[ 1]=v0.w; py[ 1]=v1.x; pz[ 1]=v1.y;
    px[ 2]=v1.z; py[ 2]=v1.w; pz[ 2]=v2.x;
    px[ 3]=v2.y; py[ 3]=v2.z; pz[ 3]=v2.w;
    px[ 4]=v3.x; py[ 4]=v3.y; pz[ 4]=v3.z;
    px[ 5]=v3.w; py[ 5]=v4.x; pz[ 5]=v4.y;
    px[ 6]=v4.z; py[ 6]=v4.w; pz[ 6]=v5.x;
    px[ 7]=v5.y; py[ 7]=v5.z; pz[ 7]=v5.w;
    px[ 8]=v6.x; py[ 8]=v6.y; pz[ 8]=v6.z;
    px[ 9]=v6.w; py[ 9]=v7.x; pz[ 9]=v7.y;
    px[10]=v7.z; py[10]=v7.w; pz[10]=v8.x;
    px[11]=v8.y; py[11]=v8.z; pz[11]=v8.w;
    px[12]=v9.x; py[12]=v9.y; pz[12]=v9.z;
    px[13]=v9.w; py[13]=v10.x; pz[13]=v10.y;
    px[14]=v10.z; py[14]=v10.w; pz[14]=v11.x;
    px[15]=v11.y; py[15]=v11.z; pz[15]=v11.w;
  }
  #pragma unroll
  for (int r = 0; r < 16; ++r) dist[r] = 10000000000.0f;

  __shared__ __align__(16) float part[2][8][8];  // ping-pong (v,idx,x,y,z,pad)
  __shared__ float out_lds[NSAMP * 3];           // centroids, flushed at end

  const int lane = t & 63;
  const int wv   = t >> 6;

  float cx = bx[0], cy = bx[1], cz = bx[2];  // initial centroid = point 0

  for (int it = 0; it < NSAMP; ++it) {
    if (t == 0) {
      out_lds[it * 3 + 0] = cx;
      out_lds[it * 3 + 1] = cy;
      out_lds[it * 3 + 2] = cz;
    }

    float bv = -1.0f;
    #pragma unroll
    for (int r = 0; r < 16; ++r) {
      float dx = px[r] - cx;
      float dy = py[r] - cy;
      float dz = pz[r] - cz;
      float d  = fmaf(dz, dz, fmaf(dy, dy, dx * dx));  // scan-fused rounding
      float nd = fminf(dist[r], d);
      dist[r] = nd;
      bv = fmaxf(bv, nd);
    }
    int bi = t * 16 + 15;
    #pragma unroll
    for (int r = 14; r >= 0; --r) bi = (dist[r] == bv) ? (t * 16 + r) : bi;

    // candidate coords select (independent of DPP chain -> ILP-hidden)
    int rr = bi & 15;
    float sx = px[0], sy = py[0], sz = pz[0];
    #pragma unroll
    for (int q = 1; q < 16; ++q) {
      bool e = (rr == q);
      sx = e ? px[q] : sx;
      sy = e ? py[q] : sy;
      sz = e ? pz[q] : sz;
    }

    // wave-64 max via DPP chain; lane 63 holds the wave max
    float rmax = bv;
    DPP_MAXSTEP(rmax, 0x111);  // row_shr:1
    DPP_MAXSTEP(rmax, 0x112);  // row_shr:2
    DPP_MAXSTEP(rmax, 0x114);  // row_shr:4
    DPP_MAXSTEP(rmax, 0x118);  // row_shr:8
    DPP_MAXSTEP(rmax, 0x142);  // row_bcast:15
    DPP_MAXSTEP(rmax, 0x143);  // row_bcast:31
    float vmax = __int_as_float(
        __builtin_amdgcn_readlane(__float_as_int(rmax), 63));

    unsigned long long m = __ballot(bv == vmax);
    int L = __ffsll((long long)m) - 1;

    const int slot = it & 1;
    if (lane == L) {               // winning lane: bv==vmax, bi==wave argmax
      float* s = &part[slot][wv][0];
      *(float4*)s = make_float4(vmax, __uint_as_float((unsigned)bi), sx, sy);
      s[4] = sz;
    }
    __syncthreads();   // the ONLY barrier; ping-pong makes it WAR-safe

    // rolling select over 8 partials (broadcast LDS reads); strict > keeps
    // lowest wave = lowest index on exact ties
    const float4* pp = (const float4*)&part[slot][0][0];
    float4 a = pp[0], bq = pp[1];
    float v = a.x; float x = a.z, y = a.w, z = bq.x;
    #pragma unroll
    for (int s = 1; s < 8; ++s) {
      float4 c0 = pp[2 * s], c1 = pp[2 * s + 1];
      bool g = (c0.x > v);
      v = g ? c0.x : v;
      x = g ? c0.z : x;
      y = g ? c0.w : y;
      z = g ? c1.x : z;
    }
    cx = x; cy = y; cz = z;        // next centroid, no global load
  }

  __syncthreads();
  float* ob = out_sampled + (size_t)b * NSAMP * 3;
  for (int i = t; i < NSAMP * 3; i += 512) ob[i] = out_lds[i];
}

// ---------------------------------------------------------------------------
// Kernel 2: query_ball_point. One wave per centroid, ballot-prefix append,
// early exit once 32 found. EAGER reference rounding (bit-exact, DO NOT TOUCH)
// ---------------------------------------------------------------------------
__global__ __launch_bounds__(256) void ball_kernel(
    const float* __restrict__ xyz, const float* __restrict__ sampled,
    int* __restrict__ gidx)
{
  #pragma clang fp contract(off)
  const float R2 = (float)(0.2 * 0.2);
  int gt = blockIdx.x * 256 + threadIdx.x;
  int w = gt >> 6;                // centroid id, 0..16383
  int lane = gt & 63;
  const int b = w >> 10;
  const float* cp = sampled + (size_t)w * 3;
  float cx = cp[0], cy = cp[1], cz = cp[2];
  float na = ((cx * cx) + (cy * cy)) + (cz * cz);   // eager: plain adds
  const float* bx = xyz + (size_t)b * N_PTS * 3;
  int* out = gidx + (size_t)w * NGRP;

  int cnt = 0;
  int first = 0;
  for (int base = 0; base < N_PTS && cnt < NGRP; base += 64) {
    int p = base + lane;
    float x = bx[p * 3 + 0];
    float y = bx[p * 3 + 1];
    float z = bx[p * 3 + 2];
    float nb  = ((x * x) + (y * y)) + (z * z);      // eager: plain adds
    float dot = fmaf(cz, z, fmaf(cy, y, cx * x));   // Eigen fma chain
    float sq  = (na + nb) - (2.0f * dot);
    bool inr = !(sq > R2);
    unsigned long long m = __ballot(inr);
    if (cnt == 0 && m != 0ull) first = base + (__ffsll(m) - 1);
    int before = __popcll(m & ((1ull << lane) - 1ull));
    int pos = cnt + before;
    if (inr && pos < NGRP) out[pos] = p;
    cnt += __popcll(m);
  }
  if (cnt < NGRP) {
    int q = cnt + lane;
    if (q < NGRP) out[q] = first;
  }
}

// ---------------------------------------------------------------------------
// Kernel 3: gather + MLP(67->64->128->256, relu) + max over 32 points.
// One 256-thread block per centroid. Transposed LDS tiles [c][k], stride 36.
// k in LOW thread bits (kg = t&7 / kq = t&3):
//   - reads spread over 8/4 bank-windows (<=4-way, cheap) instead of pure
//     broadcast, stores drop from 16-way (R6 bug) to 4-way conflicts
//   - 4-way j-blocking on L2/L3 halves ds_read_b128 count vs R5
//     (1548/block vs 2828); weights load as one float2/float4
// FMA chain per output: c ascending, bias init — matches XLA eager dot
// (bit-exact, DO NOT REORDER). fmax pool reassociation is bit-safe (no NaN).
// ---------------------------------------------------------------------------
__global__ __launch_bounds__(256, 4) void mlp_kernel(
    const float* __restrict__ xyz, const float* __restrict__ fea,
    const float* __restrict__ sampled, const int* __restrict__ gidx,
    const float* __restrict__ W1, const float* __restrict__ b1,
    const float* __restrict__ W2, const float* __restrict__ b2,
    const float* __restrict__ W3, const float* __restrict__ b3,
    float* __restrict__ out)
{
  __shared__ float fT[67][36];     // feats^T  [c][k]; reused as pmax later
  __shared__ float h1T[64][36];    // h1^T     [c][k]
  __shared__ float h2T[128][36];   // h2^T     [c][k]
  __shared__ int   sidx[32];
  __shared__ float sc[4];

  const int bs = blockIdx.x;        // b*1024 + s
  const int b  = bs >> 10;
  const int t  = threadIdx.x;

  if (t < 32) sidx[t] = gidx[(size_t)bs * 32 + t];
  if (t < 3)  sc[t] = sampled[(size_t)bs * 3 + t];
  __syncthreads();

  // gather: rel(3) ++ fea(64) -> fT[c][k]
  {
    const int k = t >> 3, c0 = t & 7;
    const int p = sidx[k];
    const float* xp = xyz + ((size_t)b * N_PTS + p) * 3;
    const float* fp = fea + ((size_t)b * N_PTS + p) * 64;
    for (int c = c0; c < 67; c += 8) {
      float v = (c < 3) ? (xp[c] - sc[c]) : fp[c - 3];
      fT[c][k] = v;
    }
  }
  __syncthreads();

  // layer 1: 2-way j. kg = t&7 (4 points), j0 = t>>3 -> outputs 2j0, 2j0+1.
  {
    const int kg = t & 7, j0 = t >> 3;
    float a0[4], a1[4];
    float2 bb = *(const float2*)&b1[2 * j0];
    #pragma unroll
    for (int r = 0; r < 4; ++r) { a0[r] = bb.x; a1[r] = bb.y; }
    for (int c = 0; c < 67; ++c) {
      float2 w = *(const float2*)&W1[c * 64 + 2 * j0];
      float4 f = *(const float4*)&fT[c][kg * 4];
      a0[0] = fmaf(f.x, w.x, a0[0]);  a1[0] = fmaf(f.x, w.y, a1[0]);
      a0[1] = fmaf(f.y, w.x, a0[1]);  a1[1] = fmaf(f.y, w.y, a1[1]);
      a0[2] = fmaf(f.z, w.x, a0[2]);  a1[2] = fmaf(f.z, w.y, a1[2]);
      a0[3] = fmaf(f.w, w.x, a0[3]);  a1[3] = fmaf(f.w, w.y, a1[3]);
    }
    *(float4*)&h1T[2 * j0][kg * 4] =
        make_float4(fmaxf(a0[0], 0.0f), fmaxf(a0[1], 0.0f),
                    fmaxf(a0[2], 0.0f), fmaxf(a0[3], 0.0f));
    *(float4*)&h1T[2 * j0 + 1][kg * 4] =
        make_float4(fmaxf(a1[0], 0.0f), fmaxf(a1[1], 0.0f),
                    fmaxf(a1[2], 0.0f), fmaxf(a1[3], 0.0f));
  }
  __syncthreads();

  // layer 2: 4-way j. kg = t&7 (4 points), j0 = t>>3 -> outputs 4j0..4j0+3.
  {
    const int kg = t & 7, j0 = t >> 3;
    float a[4][4];
    float4 bb = *(const float4*)&b2[4 * j0];
    #pragma unroll
    for (int r = 0; r < 4; ++r) { a[0][r] = bb.x; a[1][r] = bb.y; a[2][r] = bb.z; a[3][r] = bb.w; }
    for (int c = 0; c < 64; ++c) {
      float4 w = *(const float4*)&W2[c * 128 + 4 * j0];
      float4 f = *(const float4*)&h1T[c][kg * 4];
      a[0][0] = fmaf(f.x, w.x, a[0][0]);  a[1][0] = fmaf(f.x, w.y, a[1][0]);
      a[2][0] = fmaf(f.x, w.z, a[2][0]);  a[3][0] = fmaf(f.x, w.w, a[3][0]);
      a[0][1] = fmaf(f.y, w.x, a[0][1]);  a[1][1] = fmaf(f.y, w.y, a[1][1]);
      a[2][1] = fmaf(f.y, w.z, a[2][1]);  a[3][1] = fmaf(f.y, w.w, a[3][1]);
      a[0][2] = fmaf(f.z, w.x, a[0][2]);  a[1][2] = fmaf(f.z, w.y, a[1][2]);
      a[2][2] = fmaf(f.z, w.z, a[2][2]);  a[3][2] = fmaf(f.z, w.w, a[3][2]);
      a[0][3] = fmaf(f.w, w.x, a[0][3]);  a[1][3] = fmaf(f.w, w.y, a[1][3]);
      a[2][3] = fmaf(f.w, w.z, a[2][3]);  a[3][3] = fmaf(f.w, w.w, a[3][3]);
    }
    #pragma unroll
    for (int q = 0; q < 4; ++q) {
      *(float4*)&h2T[4 * j0 + q][kg * 4] =
          make_float4(fmaxf(a[q][0], 0.0f), fmaxf(a[q][1], 0.0f),
                      fmaxf(a[q][2], 0.0f), fmaxf(a[q][3], 0.0f));
    }
  }
  __syncthreads();

  // layer 3 + pool: 4-way j. kq = t&3 (8 points), j0 = t>>2 -> 4j0..4j0+3.
  float* pmax = &fT[0][0];   // 4*256 floats, reuse (fT dead since layer 1)
  {
    const int kq = t & 3, j0 = t >> 2;
    float a[4][8];
    float4 bb = *(const float4*)&b3[4 * j0];
    #pragma unroll
    for (int r = 0; r < 8; ++r) { a[0][r] = bb.x; a[1][r] = bb.y; a[2][r] = bb.z; a[3][r] = bb.w; }
    for (int c = 0; c < 128; ++c) {
      float4 w = *(const float4*)&W3[c * 256 + 4 * j0];
      const float4* hp = (const float4*)&h2T[c][kq * 8];
      float4 f0 = hp[0], f1 = hp[1];
      #pragma unroll
      for (int q = 0; q < 4; ++q) {
        float wq = (q == 0) ? w.x : (q == 1) ? w.y : (q == 2) ? w.z : w.w;
        a[q][0] = fmaf(f0.x, wq, a[q][0]);
        a[q][1] = fmaf(f0.y, wq, a[q][1]);
        a[q][2] = fmaf(f0.z, wq, a[q][2]);
        a[q][3] = fmaf(f0.w, wq, a[q][3]);
        a[q][4] = fmaf(f1.x, wq, a[q][4]);
        a[q][5] = fmaf(f1.y, wq, a[q][5]);
        a[q][6] = fmaf(f1.z, wq, a[q][6]);
        a[q][7] = fmaf(f1.w, wq, a[q][7]);
      }
    }
    float m[4];
    #pragma unroll
    for (int q = 0; q < 4; ++q) {
      m[q] = a[q][0];
      #pragma unroll
      for (int r = 1; r < 8; ++r) m[q] = fmaxf(m[q], a[q][r]);
    }
    *(float4*)&pmax[kq * 256 + 4 * j0] = make_float4(m[0], m[1], m[2], m[3]);
  }
  __syncthreads();

  {
    float v = fmaxf(fmaxf(pmax[t], pmax[256 + t]),
                    fmaxf(pmax[512 + t], pmax[768 + t]));
    out[(size_t)bs * 256 + t] = fmaxf(v, 0.0f);   // relu(max) == max(relu)
  }
}

// ---------------------------------------------------------------------------
extern "C" void kernel_launch(void* const* d_in, const int* in_sizes, int n_in,
                              void* d_out, int out_size, void* d_ws, size_t ws_size,
                              hipStream_t stream) {
  const float* xyz = (const float*)d_in[0];
  const float* fea = (const float*)d_in[1];
  const float* W1  = (const float*)d_in[2];
  const float* b1  = (const float*)d_in[3];
  const float* W2  = (const float*)d_in[4];
  const float* b2  = (const float*)d_in[5];
  const float* W3  = (const float*)d_in[6];
  const float* b3  = (const float*)d_in[7];

  float* outp    = (float*)d_out;
  float* sampled = outp;                    // output 0: (16,1024,3)
  float* mlp_out = outp + 16 * 1024 * 3;    // output 1: (16,1024,256)
  int*   gidx    = (int*)d_ws;              // 16384*32 ints = 2 MB scratch

  fps_kernel<<<16, 512, 0, stream>>>(xyz, sampled);
  ball_kernel<<<4096, 256, 0, stream>>>(xyz, sampled, gidx);
  mlp_kernel<<<16384, 256, 0, stream>>>(xyz, fea, sampled, gidx,
                                        W1, b1, W2, b2, W3, b3, mlp_out);
}

// Round 9
// 1787.823 us; speedup vs baseline: 1.2406x; 1.2406x over previous
//
#include <hip/hip_runtime.h>

#define N_PTS 8192
#define NSAMP 1024
#define NGRP  32

// DPP max step: invalid lanes keep 'old' (=r), identity for max.
#define DPP_MAXSTEP(r, ctrl)                                                  \
  r = fmaxf(r, __int_as_float(__builtin_amdgcn_update_dpp(                    \
          __float_as_int(r), __float_as_int(r), (ctrl), 0xf, 0xf, false)))

#define READLANE_F(x, L) \
  __int_as_float(__builtin_amdgcn_readlane(__float_as_int(x), (L)))

// ---------------------------------------------------------------------------
// Kernel 1: farthest point sampling. One block of 512 threads (8 waves) per
// batch; each thread owns 16 consecutive points in registers.
// Distance rounding matches XLA:CPU's scan-compiled contracted reduce:
//   d = fma(dz,dz, fma(dy,dy, dx*dx))          (bit-exact, DO NOT TOUCH)
// argmax ties -> lowest index.
//
// Structure = R7 (proven 859us): DPP max chain, ballot lowest-lane tie,
// lane-0 single vector publish, upfront independent LDS loads, ALU-only
// rolling scan. R9 delta: publish (v,x,y,z) in ONE float4 (coords via 3
// readlanes from winning lane; candidate select overlaps the DPP chain),
// so the scan yields the next centroid directly -- the dependent global
// centroid load (~L2 latency) leaves the serial chain. R8's 5-scalar/16-load
// interleaved variant regressed 1.8x; this keeps R7's load-all-then-ALU shape.
// ---------------------------------------------------------------------------
__global__
__attribute__((amdgpu_flat_work_group_size(512, 512)))
__attribute__((amdgpu_waves_per_eu(2, 2)))
void fps_kernel(
    const float* __restrict__ xyz, float* __restrict__ out_sampled)
{
  #pragma clang fp contract(off)
  const int b = blockIdx.x;
  const int t = threadIdx.x;
  const float* bx = xyz + (size_t)b * N_PTS * 3;

  float px[16], py[16], pz[16], dist[16];
  {
    const float4* src = (const float4*)(bx + t * 48);
    float4 v0 = src[0], v1 = src[1], v2 = src[2];
    float4 v3 = src[3], v4 = src[4], v5 = src[5];
    float4 v6 = src[6], v7 = src[7], v8 = src[8];
    float4 v9 = src[9], v10 = src[10], v11 = src[11];
    px[ 0]=v0.x; py[ 0]=v0.y; pz[ 0]=v0.z;
    px[ 1]=v0.w; py[ 1]=v1.x; pz[ 1]=v1.y;
    px[ 2]=v1.z; py[ 2]=v1.w; pz[ 2]=v2.x;
    px[ 3]=v2.y; py[ 3]=v2.z; pz[ 3]=v2.w;
    px[ 4]=v3.x; py[ 4]=v3.y; pz[ 4]=v3.z;
    px[ 5]=v3.w; py[ 5]=v4.x; pz[ 5]=v4.y;
    px[ 6]=v4.z; py[ 6]=v4.w; pz[ 6]=v5.x;
    px[ 7]=v5.y; py[ 7]=v5.z; pz[ 7]=v5.w;
    px[ 8]=v6.x; py[ 8]=v6.y; pz[ 8]=v6.z;
    px[ 9]=v6.w; py[ 9]=v7.x; pz[ 9]=v7.y;
    px[10]=v7.z; py[10]=v7.w; pz[10]=v8.x;
    px[11]=v8.y; py[11]=v8.z; pz[11]=v8.w;
    px[12]=v9.x; py[12]=v9.y; pz[12]=v9.z;
    px[13]=v9.w; py[13]=v10.x; pz[13]=v10.y;
    px[14]=v10.z; py[14]=v10.w; pz[14]=v11.x;
    px[15]=v11.y; py[15]=v11.z; pz[15]=v11.w;
  }
  #pragma unroll
  for (int r = 0; r < 16; ++r) dist[r] = 10000000000.0f;

  __shared__ __align__(16) float4 part[2][8];  // ping-pong (v, x, y, z)
  __shared__ float out_lds[NSAMP * 3];         // centroids, flushed at end

  const int lane = t & 63;
  const int wv   = t >> 6;

  float cx = bx[0], cy = bx[1], cz = bx[2];  // initial centroid = point 0

  for (int it = 0; it < NSAMP; ++it) {
    if (t == 0) {
      out_lds[it * 3 + 0] = cx;
      out_lds[it * 3 + 1] = cy;
      out_lds[it * 3 + 2] = cz;
    }

    float bv = -1.0f;
    #pragma unroll
    for (int r = 0; r < 16; ++r) {
      float dx = px[r] - cx;
      float dy = py[r] - cy;
      float dz = pz[r] - cz;
      float d  = fmaf(dz, dz, fmaf(dy, dy, dx * dx));  // scan-fused rounding
      float nd = fminf(dist[r], d);
      dist[r] = nd;
      bv = fmaxf(bv, nd);
    }
    int bi = t * 16 + 15;
    #pragma unroll
    for (int r = 14; r >= 0; --r) bi = (dist[r] == bv) ? (t * 16 + r) : bi;

    // candidate coords select (independent of DPP chain -> overlaps it)
    int rr = bi & 15;
    float sx = px[0], sy = py[0], sz = pz[0];
    #pragma unroll
    for (int q = 1; q < 16; ++q) {
      bool e = (rr == q);
      sx = e ? px[q] : sx;
      sy = e ? py[q] : sy;
      sz = e ? pz[q] : sz;
    }

    // wave-64 max via DPP chain; lane 63 holds the wave max
    float rmax = bv;
    DPP_MAXSTEP(rmax, 0x111);  // row_shr:1
    DPP_MAXSTEP(rmax, 0x112);  // row_shr:2
    DPP_MAXSTEP(rmax, 0x114);  // row_shr:4
    DPP_MAXSTEP(rmax, 0x118);  // row_shr:8
    DPP_MAXSTEP(rmax, 0x142);  // row_bcast:15
    DPP_MAXSTEP(rmax, 0x143);  // row_bcast:31
    float vmax = __int_as_float(
        __builtin_amdgcn_readlane(__float_as_int(rmax), 63));

    // lowest lane holding the max (lane order == index order)
    unsigned long long m = __ballot(bv == vmax);
    int L = __ffsll((long long)m) - 1;
    float wx = READLANE_F(sx, L);
    float wy = READLANE_F(sy, L);
    float wz = READLANE_F(sz, L);

    const int slot = it & 1;
    if (lane == 0) part[slot][wv] = make_float4(vmax, wx, wy, wz);
    __syncthreads();   // the ONLY barrier; ping-pong makes it WAR-safe

    // 8 independent upfront loads, then ALU-only rolling select;
    // strict > keeps lowest wave = lowest index on exact ties
    const float4* pp = &part[slot][0];
    float4 q0 = pp[0], q1 = pp[1], q2 = pp[2], q3 = pp[3];
    float4 q4 = pp[4], q5 = pp[5], q6 = pp[6], q7 = pp[7];
    float v = q0.x;
    float x = q0.y, y = q0.z, z = q0.w;
    bool g;
    g = (q1.x > v); v = g ? q1.x : v; x = g ? q1.y : x; y = g ? q1.z : y; z = g ? q1.w : z;
    g = (q2.x > v); v = g ? q2.x : v; x = g ? q2.y : x; y = g ? q2.z : y; z = g ? q2.w : z;
    g = (q3.x > v); v = g ? q3.x : v; x = g ? q3.y : x; y = g ? q3.z : y; z = g ? q3.w : z;
    g = (q4.x > v); v = g ? q4.x : v; x = g ? q4.y : x; y = g ? q4.z : y; z = g ? q4.w : z;
    g = (q5.x > v); v = g ? q5.x : v; x = g ? q5.y : x; y = g ? q5.z : y; z = g ? q5.w : z;
    g = (q6.x > v); v = g ? q6.x : v; x = g ? q6.y : x; y = g ? q6.z : y; z = g ? q6.w : z;
    g = (q7.x > v); v = g ? q7.x : v; x = g ? q7.y : x; y = g ? q7.z : y; z = g ? q7.w : z;
    cx = x; cy = y; cz = z;        // next centroid, no global load

  }

  __syncthreads();
  float* ob = out_sampled + (size_t)b * NSAMP * 3;
  for (int i = t; i < NSAMP * 3; i += 512) ob[i] = out_lds[i];
}

// ---------------------------------------------------------------------------
// Kernel 2: query_ball_point. One wave per centroid, ballot-prefix append,
// early exit once 32 found. EAGER reference rounding (bit-exact, DO NOT TOUCH)
// ---------------------------------------------------------------------------
__global__ __launch_bounds__(256) void ball_kernel(
    const float* __restrict__ xyz, const float* __restrict__ sampled,
    int* __restrict__ gidx)
{
  #pragma clang fp contract(off)
  const float R2 = (float)(0.2 * 0.2);
  int gt = blockIdx.x * 256 + threadIdx.x;
  int w = gt >> 6;                // centroid id, 0..16383
  int lane = gt & 63;
  const int b = w >> 10;
  const float* cp = sampled + (size_t)w * 3;
  float cx = cp[0], cy = cp[1], cz = cp[2];
  float na = ((cx * cx) + (cy * cy)) + (cz * cz);   // eager: plain adds
  const float* bx = xyz + (size_t)b * N_PTS * 3;
  int* out = gidx + (size_t)w * NGRP;

  int cnt = 0;
  int first = 0;
  for (int base = 0; base < N_PTS && cnt < NGRP; base += 64) {
    int p = base + lane;
    float x = bx[p * 3 + 0];
    float y = bx[p * 3 + 1];
    float z = bx[p * 3 + 2];
    float nb  = ((x * x) + (y * y)) + (z * z);      // eager: plain adds
    float dot = fmaf(cz, z, fmaf(cy, y, cx * x));   // Eigen fma chain
    float sq  = (na + nb) - (2.0f * dot);
    bool inr = !(sq > R2);
    unsigned long long m = __ballot(inr);
    if (cnt == 0 && m != 0ull) first = base + (__ffsll(m) - 1);
    int before = __popcll(m & ((1ull << lane) - 1ull));
    int pos = cnt + before;
    if (inr && pos < NGRP) out[pos] = p;
    cnt += __popcll(m);
  }
  if (cnt < NGRP) {
    int q = cnt + lane;
    if (q < NGRP) out[q] = first;
  }
}

// ---------------------------------------------------------------------------
// Kernel 3: gather + MLP(67->64->128->256, relu) + max over 32 points.
// Exact R5 version (fastest measured aux): 2-way j-register-blocking,
// k in HIGH thread bits, transposed LDS tiles [c][k] stride 36.
// FMA chain per output: c ascending, bias init (bit-exact, DO NOT REORDER).
// ---------------------------------------------------------------------------
__global__ __launch_bounds__(256, 4) void mlp_kernel(
    const float* __restrict__ xyz, const float* __restrict__ fea,
    const float* __restrict__ sampled, const int* __restrict__ gidx,
    const float* __restrict__ W1, const float* __restrict__ b1,
    const float* __restrict__ W2, const float* __restrict__ b2,
    const float* __restrict__ W3, const float* __restrict__ b3,
    float* __restrict__ out)
{
  __shared__ float fT[67][36];     // feats^T  [c][k]
  __shared__ float h1T[64][36];    // h1^T     [c][k]
  __shared__ float h2T[128][36];   // h2^T     [c][k]
  __shared__ float pmax[2][256];   // layer-3 partial maxes per k-half
  __shared__ int   sidx[32];
  __shared__ float sc[4];

  const int bs = blockIdx.x;        // b*1024 + s
  const int b  = bs >> 10;
  const int t  = threadIdx.x;

  if (t < 32) sidx[t] = gidx[(size_t)bs * 32 + t];
  if (t < 3)  sc[t] = sampled[(size_t)bs * 3 + t];
  __syncthreads();

  // gather: rel(3) ++ fea(64) -> fT[c][k]
  {
    const int k = t >> 3, c0 = t & 7;
    const int p = sidx[k];
    const float* xp = xyz + ((size_t)b * N_PTS + p) * 3;
    const float* fp = fea + ((size_t)b * N_PTS + p) * 64;
    for (int c = c0; c < 67; c += 8) {
      float v = (c < 3) ? (xp[c] - sc[c]) : fp[c - 3];
      fT[c][k] = v;
    }
  }
  __syncthreads();

  // layer 1: outputs (j0, j0+32), 4 points each. j0 = t&31, kq = t>>5.
  {
    const int j0 = t & 31, kq = t >> 5;
    float a0[4], a1[4];
    float bb0 = b1[j0], bb1 = b1[j0 + 32];
    #pragma unroll
    for (int r = 0; r < 4; ++r) { a0[r] = bb0; a1[r] = bb1; }
    for (int c = 0; c < 67; ++c) {
      float w0 = W1[c * 64 + j0];
      float w1 = W1[c * 64 + j0 + 32];
      float4 f = *(const float4*)&fT[c][kq * 4];
      a0[0] = fmaf(f.x, w0, a0[0]);  a1[0] = fmaf(f.x, w1, a1[0]);
      a0[1] = fmaf(f.y, w0, a0[1]);  a1[1] = fmaf(f.y, w1, a1[1]);
      a0[2] = fmaf(f.z, w0, a0[2]);  a1[2] = fmaf(f.z, w1, a1[2]);
      a0[3] = fmaf(f.w, w0, a0[3]);  a1[3] = fmaf(f.w, w1, a1[3]);
    }
    float* d0 = &h1T[j0][kq * 4];
    float* d1 = &h1T[j0 + 32][kq * 4];
    #pragma unroll
    for (int r = 0; r < 4; ++r) { d0[r] = fmaxf(a0[r], 0.0f); d1[r] = fmaxf(a1[r], 0.0f); }
  }
  __syncthreads();

  // layer 2: outputs (j0, j0+64), 8 points each. j0 = t&63, kh = t>>6.
  {
    const int j0 = t & 63, kh = t >> 6;
    float a0[8], a1[8];
    float bb0 = b2[j0], bb1 = b2[j0 + 64];
    #pragma unroll
    for (int r = 0; r < 8; ++r) { a0[r] = bb0; a1[r] = bb1; }
    for (int c = 0; c < 64; ++c) {
      float w0 = W2[c * 128 + j0];
      float w1 = W2[c * 128 + j0 + 64];
      const float4* hp = (const float4*)&h1T[c][kh * 8];
      float4 f0 = hp[0], f1 = hp[1];
      a0[0] = fmaf(f0.x, w0, a0[0]);  a1[0] = fmaf(f0.x, w1, a1[0]);
      a0[1] = fmaf(f0.y, w0, a0[1]);  a1[1] = fmaf(f0.y, w1, a1[1]);
      a0[2] = fmaf(f0.z, w0, a0[2]);  a1[2] = fmaf(f0.z, w1, a1[2]);
      a0[3] = fmaf(f0.w, w0, a0[3]);  a1[3] = fmaf(f0.w, w1, a1[3]);
      a0[4] = fmaf(f1.x, w0, a0[4]);  a1[4] = fmaf(f1.x, w1, a1[4]);
      a0[5] = fmaf(f1.y, w0, a0[5]);  a1[5] = fmaf(f1.y, w1, a1[5]);
      a0[6] = fmaf(f1.z, w0, a0[6]);  a1[6] = fmaf(f1.z, w1, a1[6]);
      a0[7] = fmaf(f1.w, w0, a0[7]);  a1[7] = fmaf(f1.w, w1, a1[7]);
    }
    float* d0 = &h2T[j0][kh * 8];
    float* d1 = &h2T[j0 + 64][kh * 8];
    #pragma unroll
    for (int r = 0; r < 8; ++r) { d0[r] = fmaxf(a0[r], 0.0f); d1[r] = fmaxf(a1[r], 0.0f); }
  }
  __syncthreads();

  // layer 3 + max-pool: outputs (j0, j0+128), 16 points each. kh = t>>7.
  {
    const int j0 = t & 127, kh = t >> 7;
    float a0[16], a1[16];
    float bb0 = b3[j0], bb1 = b3[j0 + 128];
    #pragma unroll
    for (int r = 0; r < 16; ++r) { a0[r] = bb0; a1[r] = bb1; }
    for (int c = 0; c < 128; ++c) {
      float w0 = W3[c * 256 + j0];
      float w1 = W3[c * 256 + j0 + 128];
      const float4* hp = (const float4*)&h2T[c][kh * 16];
      #pragma unroll
      for (int q = 0; q < 4; ++q) {
        float4 f = hp[q];
        a0[q*4+0] = fmaf(f.x, w0, a0[q*4+0]);  a1[q*4+0] = fmaf(f.x, w1, a1[q*4+0]);
        a0[q*4+1] = fmaf(f.y, w0, a0[q*4+1]);  a1[q*4+1] = fmaf(f.y, w1, a1[q*4+1]);
        a0[q*4+2] = fmaf(f.z, w0, a0[q*4+2]);  a1[q*4+2] = fmaf(f.z, w1, a1[q*4+2]);
        a0[q*4+3] = fmaf(f.w, w0, a0[q*4+3]);  a1[q*4+3] = fmaf(f.w, w1, a1[q*4+3]);
      }
    }
    float m0 = a0[0], m1 = a1[0];
    #pragma unroll
    for (int r = 1; r < 16; ++r) { m0 = fmaxf(m0, a0[r]); m1 = fmaxf(m1, a1[r]); }
    pmax[kh][j0]       = m0;
    pmax[kh][j0 + 128] = m1;
  }
  __syncthreads();

  {
    float v = fmaxf(pmax[0][t], pmax[1][t]);
    out[(size_t)bs * 256 + t] = fmaxf(v, 0.0f);   // relu(max) == max(relu)
  }
}

// ---------------------------------------------------------------------------
extern "C" void kernel_launch(void* const* d_in, const int* in_sizes, int n_in,
                              void* d_out, int out_size, void* d_ws, size_t ws_size,
                              hipStream_t stream) {
  const float* xyz = (const float*)d_in[0];
  const float* fea = (const float*)d_in[1];
  const float* W1  = (const float*)d_in[2];
  const float* b1  = (const float*)d_in[3];
  const float* W2  = (const float*)d_in[4];
  const float* b2  = (const float*)d_in[5];
  const float* W3  = (const float*)d_in[6];
  const float* b3  = (const float*)d_in[7];

  float* outp    = (float*)d_out;
  float* sampled = outp;                    // output 0: (16,1024,3)
  float* mlp_out = outp + 16 * 1024 * 3;    // output 1: (16,1024,256)
  int*   gidx    = (int*)d_ws;              // 16384*32 ints = 2 MB scratch

  fps_kernel<<<16, 512, 0, stream>>>(xyz, sampled);
  ball_kernel<<<4096, 256, 0, stream>>>(xyz, sampled, gidx);
  mlp_kernel<<<16384, 256, 0, stream>>>(xyz, fea, sampled, gidx,
                                        W1, b1, W2, b2, W3, b3, mlp_out);
}

// Round 10
// 1570.553 us; speedup vs baseline: 1.4122x; 1.1383x over previous
//
#include <hip/hip_runtime.h>

#define N_PTS 8192
#define NSAMP 1024
#define NGRP  32

typedef float v2f __attribute__((ext_vector_type(2)));

// DPP max step: invalid lanes keep 'old' (=r), identity for max.
#define DPP_MAXSTEP(r, ctrl)                                                  \
  r = fmaxf(r, __int_as_float(__builtin_amdgcn_update_dpp(                    \
          __float_as_int(r), __float_as_int(r), (ctrl), 0xf, 0xf, false)))

// ---------------------------------------------------------------------------
// Kernel 1: farthest point sampling. One block of 512 threads (8 waves) per
// batch; each thread owns 16 consecutive points in registers (as 8 float2
// pairs so the backend can emit V_PK_ADD/MUL/FMA_F32 packed fp32 ops).
//
// MODEL (R5/R7/R8/R9 evidence): this kernel is VALU-ISSUE-bound at ~91% of
// the active-CU ceiling. Structure below = R7 exactly (proven 859us floor);
// the only change is the distance update in packed fp32 (pk ops are per-half
// IEEE-identical to the scalar chain -> bit-exact):
//   d = fma(dz,dz, fma(dy,dy, dx*dx))   per half  (DO NOT TOUCH)
// argmax ties -> lowest index. bv via max-tree (max is associative; no NaNs).
// Do NOT add cndmask select chains or extra readlanes (R8/R9 regressions).
// ---------------------------------------------------------------------------
__global__
__attribute__((amdgpu_flat_work_group_size(512, 512)))
__attribute__((amdgpu_waves_per_eu(2, 2)))
void fps_kernel(
    const float* __restrict__ xyz, float* __restrict__ out_sampled)
{
  #pragma clang fp contract(off)
  const int b = blockIdx.x;
  const int t = threadIdx.x;
  const float* bx = xyz + (size_t)b * N_PTS * 3;

  v2f pxv[8], pyv[8], pzv[8], dv[8];
  {
    const float4* src = (const float4*)(bx + t * 48);
    float4 v0 = src[0], v1 = src[1], v2 = src[2];
    float4 v3 = src[3], v4 = src[4], v5 = src[5];
    float4 v6 = src[6], v7 = src[7], v8 = src[8];
    float4 v9 = src[9], v10 = src[10], v11 = src[11];
    // point p -> pair p>>1, half p&1   (p0,p1) per pair
    pxv[0][0]=v0.x;  pyv[0][0]=v0.y;  pzv[0][0]=v0.z;
    pxv[0][1]=v0.w;  pyv[0][1]=v1.x;  pzv[0][1]=v1.y;
    pxv[1][0]=v1.z;  pyv[1][0]=v1.w;  pzv[1][0]=v2.x;
    pxv[1][1]=v2.y;  pyv[1][1]=v2.z;  pzv[1][1]=v2.w;
    pxv[2][0]=v3.x;  pyv[2][0]=v3.y;  pzv[2][0]=v3.z;
    pxv[2][1]=v3.w;  pyv[2][1]=v4.x;  pzv[2][1]=v4.y;
    pxv[3][0]=v4.z;  pyv[3][0]=v4.w;  pzv[3][0]=v5.x;
    pxv[3][1]=v5.y;  pyv[3][1]=v5.z;  pzv[3][1]=v5.w;
    pxv[4][0]=v6.x;  pyv[4][0]=v6.y;  pzv[4][0]=v6.z;
    pxv[4][1]=v6.w;  pyv[4][1]=v7.x;  pzv[4][1]=v7.y;
    pxv[5][0]=v7.z;  pyv[5][0]=v7.w;  pzv[5][0]=v8.x;
    pxv[5][1]=v8.y;  pyv[5][1]=v8.z;  pzv[5][1]=v8.w;
    pxv[6][0]=v9.x;  pyv[6][0]=v9.y;  pzv[6][0]=v9.z;
    pxv[6][1]=v9.w;  pyv[6][1]=v10.x; pzv[6][1]=v10.y;
    pxv[7][0]=v10.z; pyv[7][0]=v10.w; pzv[7][0]=v11.x;
    pxv[7][1]=v11.y; pyv[7][1]=v11.z; pzv[7][1]=v11.w;
  }
  #pragma unroll
  for (int q = 0; q < 8; ++q) dv[q] = (v2f){10000000000.0f, 10000000000.0f};

  __shared__ uint2 part[2][8];          // ping-pong (value bits, index)
  __shared__ float out_lds[NSAMP * 3];  // centroids, flushed at end

  const int lane = t & 63;
  const int wv   = t >> 6;

  float cx = bx[0], cy = bx[1], cz = bx[2];  // initial centroid = point 0

  for (int it = 0; it < NSAMP; ++it) {
    if (t == 0) {
      out_lds[it * 3 + 0] = cx;
      out_lds[it * 3 + 1] = cy;
      out_lds[it * 3 + 2] = cz;
    }

    // packed distance update: per pair 3 pk_sub + pk_mul + 2 pk_fma,
    // scalar-half min into dv, packed max-tree for bv
    v2f cxv = {cx, cx}, cyv = {cy, cy}, czv = {cz, cz};
    v2f bm = {-1.0f, -1.0f};
    #pragma unroll
    for (int q = 0; q < 8; ++q) {
      v2f dx = pxv[q] - cxv;
      v2f dy = pyv[q] - cyv;
      v2f dz = pzv[q] - czv;
      v2f d  = __builtin_elementwise_fma(
                   dz, dz, __builtin_elementwise_fma(dy, dy, dx * dx));
      v2f nd = __builtin_elementwise_min(dv[q], d);
      dv[q] = nd;
      bm = __builtin_elementwise_max(bm, nd);
    }
    float bv = fmaxf(bm[0], bm[1]);

    // lowest local index whose (updated) dist equals the thread max
    int bi = t * 16 + 15;
    #pragma unroll
    for (int r = 14; r >= 0; --r)
      bi = (dv[r >> 1][r & 1] == bv) ? (t * 16 + r) : bi;

    // wave-64 max via DPP chain; lane 63 holds the wave max
    float rmax = bv;
    DPP_MAXSTEP(rmax, 0x111);  // row_shr:1
    DPP_MAXSTEP(rmax, 0x112);  // row_shr:2
    DPP_MAXSTEP(rmax, 0x114);  // row_shr:4
    DPP_MAXSTEP(rmax, 0x118);  // row_shr:8
    DPP_MAXSTEP(rmax, 0x142);  // row_bcast:15
    DPP_MAXSTEP(rmax, 0x143);  // row_bcast:31
    float vmax = __int_as_float(
        __builtin_amdgcn_readlane(__float_as_int(rmax), 63));

    unsigned long long m = __ballot(bv == vmax);
    int L = __ffsll((long long)m) - 1;
    int widx = __builtin_amdgcn_readlane(bi, L);

    const int slot = it & 1;
    if (lane == 0) part[slot][wv] = make_uint2(__float_as_uint(vmax), (unsigned)widx);
    __syncthreads();   // the ONLY barrier; ping-pong makes it WAR-safe

    const uint4* pp = (const uint4*)&part[slot][0];
    uint4 p0 = pp[0], p1 = pp[1], p2 = pp[2], p3 = pp[3];
    float v = __uint_as_float(p0.x); unsigned f = p0.y;
    float w1v = __uint_as_float(p0.z);
    if (w1v > v) { v = w1v; f = p0.w; }
    float w2v = __uint_as_float(p1.x);
    if (w2v > v) { v = w2v; f = p1.y; }
    float w3v = __uint_as_float(p1.z);
    if (w3v > v) { v = w3v; f = p1.w; }
    float w4v = __uint_as_float(p2.x);
    if (w4v > v) { v = w4v; f = p2.y; }
    float w5v = __uint_as_float(p2.z);
    if (w5v > v) { v = w5v; f = p2.w; }
    float w6v = __uint_as_float(p3.x);
    if (w6v > v) { v = w6v; f = p3.y; }
    float w7v = __uint_as_float(p3.z);
    if (w7v > v) { v = w7v; f = p3.w; }

    // next centroid: broadcast load (single cache line, all lanes same addr)
    cx = bx[f * 3 + 0];
    cy = bx[f * 3 + 1];
    cz = bx[f * 3 + 2];
  }

  __syncthreads();
  float* ob = out_sampled + (size_t)b * NSAMP * 3;
  for (int i = t; i < NSAMP * 3; i += 512) ob[i] = out_lds[i];
}

// ---------------------------------------------------------------------------
// Kernel 2: query_ball_point. One wave per centroid, ballot-prefix append,
// early exit once 32 found. EAGER reference rounding (bit-exact, DO NOT TOUCH)
// ---------------------------------------------------------------------------
__global__ __launch_bounds__(256) void ball_kernel(
    const float* __restrict__ xyz, const float* __restrict__ sampled,
    int* __restrict__ gidx)
{
  #pragma clang fp contract(off)
  const float R2 = (float)(0.2 * 0.2);
  int gt = blockIdx.x * 256 + threadIdx.x;
  int w = gt >> 6;                // centroid id, 0..16383
  int lane = gt & 63;
  const int b = w >> 10;
  const float* cp = sampled + (size_t)w * 3;
  float cx = cp[0], cy = cp[1], cz = cp[2];
  float na = ((cx * cx) + (cy * cy)) + (cz * cz);   // eager: plain adds
  const float* bx = xyz + (size_t)b * N_PTS * 3;
  int* out = gidx + (size_t)w * NGRP;

  int cnt = 0;
  int first = 0;
  for (int base = 0; base < N_PTS && cnt < NGRP; base += 64) {
    int p = base + lane;
    float x = bx[p * 3 + 0];
    float y = bx[p * 3 + 1];
    float z = bx[p * 3 + 2];
    float nb  = ((x * x) + (y * y)) + (z * z);      // eager: plain adds
    float dot = fmaf(cz, z, fmaf(cy, y, cx * x));   // Eigen fma chain
    float sq  = (na + nb) - (2.0f * dot);
    bool inr = !(sq > R2);
    unsigned long long m = __ballot(inr);
    if (cnt == 0 && m != 0ull) first = base + (__ffsll(m) - 1);
    int before = __popcll(m & ((1ull << lane) - 1ull));
    int pos = cnt + before;
    if (inr && pos < NGRP) out[pos] = p;
    cnt += __popcll(m);
  }
  if (cnt < NGRP) {
    int q = cnt + lane;
    if (q < NGRP) out[q] = first;
  }
}

// ---------------------------------------------------------------------------
// Kernel 3: gather + MLP(67->64->128->256, relu) + max over 32 points.
// Exact R5 version (fastest measured aux): 2-way j-register-blocking,
// k in HIGH thread bits, transposed LDS tiles [c][k] stride 36.
// FMA chain per output: c ascending, bias init (bit-exact, DO NOT REORDER).
// ---------------------------------------------------------------------------
__global__ __launch_bounds__(256, 4) void mlp_kernel(
    const float* __restrict__ xyz, const float* __restrict__ fea,
    const float* __restrict__ sampled, const int* __restrict__ gidx,
    const float* __restrict__ W1, const float* __restrict__ b1,
    const float* __restrict__ W2, const float* __restrict__ b2,
    const float* __restrict__ W3, const float* __restrict__ b3,
    float* __restrict__ out)
{
  __shared__ float fT[67][36];     // feats^T  [c][k]
  __shared__ float h1T[64][36];    // h1^T     [c][k]
  __shared__ float h2T[128][36];   // h2^T     [c][k]
  __shared__ float pmax[2][256];   // layer-3 partial maxes per k-half
  __shared__ int   sidx[32];
  __shared__ float sc[4];

  const int bs = blockIdx.x;        // b*1024 + s
  const int b  = bs >> 10;
  const int t  = threadIdx.x;

  if (t < 32) sidx[t] = gidx[(size_t)bs * 32 + t];
  if (t < 3)  sc[t] = sampled[(size_t)bs * 3 + t];
  __syncthreads();

  // gather: rel(3) ++ fea(64) -> fT[c][k]
  {
    const int k = t >> 3, c0 = t & 7;
    const int p = sidx[k];
    const float* xp = xyz + ((size_t)b * N_PTS + p) * 3;
    const float* fp = fea + ((size_t)b * N_PTS + p) * 64;
    for (int c = c0; c < 67; c += 8) {
      float v = (c < 3) ? (xp[c] - sc[c]) : fp[c - 3];
      fT[c][k] = v;
    }
  }
  __syncthreads();

  // layer 1: outputs (j0, j0+32), 4 points each. j0 = t&31, kq = t>>5.
  {
    const int j0 = t & 31, kq = t >> 5;
    float a0[4], a1[4];
    float bb0 = b1[j0], bb1 = b1[j0 + 32];
    #pragma unroll
    for (int r = 0; r < 4; ++r) { a0[r] = bb0; a1[r] = bb1; }
    for (int c = 0; c < 67; ++c) {
      float w0 = W1[c * 64 + j0];
      float w1 = W1[c * 64 + j0 + 32];
      float4 f = *(const float4*)&fT[c][kq * 4];
      a0[0] = fmaf(f.x, w0, a0[0]);  a1[0] = fmaf(f.x, w1, a1[0]);
      a0[1] = fmaf(f.y, w0, a0[1]);  a1[1] = fmaf(f.y, w1, a1[1]);
      a0[2] = fmaf(f.z, w0, a0[2]);  a1[2] = fmaf(f.z, w1, a1[2]);
      a0[3] = fmaf(f.w, w0, a0[3]);  a1[3] = fmaf(f.w, w1, a1[3]);
    }
    float* d0 = &h1T[j0][kq * 4];
    float* d1 = &h1T[j0 + 32][kq * 4];
    #pragma unroll
    for (int r = 0; r < 4; ++r) { d0[r] = fmaxf(a0[r], 0.0f); d1[r] = fmaxf(a1[r], 0.0f); }
  }
  __syncthreads();

  // layer 2: outputs (j0, j0+64), 8 points each. j0 = t&63, kh = t>>6.
  {
    const int j0 = t & 63, kh = t >> 6;
    float a0[8], a1[8];
    float bb0 = b2[j0], bb1 = b2[j0 + 64];
    #pragma unroll
    for (int r = 0; r < 8; ++r) { a0[r] = bb0; a1[r] = bb1; }
    for (int c = 0; c < 64; ++c) {
      float w0 = W2[c * 128 + j0];
      float w1 = W2[c * 128 + j0 + 64];
      const float4* hp = (const float4*)&h1T[c][kh * 8];
      float4 f0 = hp[0], f1 = hp[1];
      a0[0] = fmaf(f0.x, w0, a0[0]);  a1[0] = fmaf(f0.x, w1, a1[0]);
      a0[1] = fmaf(f0.y, w0, a0[1]);  a1[1] = fmaf(f0.y, w1, a1[1]);
      a0[2] = fmaf(f0.z, w0, a0[2]);  a1[2] = fmaf(f0.z, w1, a1[2]);
      a0[3] = fmaf(f0.w, w0, a0[3]);  a1[3] = fmaf(f0.w, w1, a1[3]);
      a0[4] = fmaf(f1.x, w0, a0[4]);  a1[4] = fmaf(f1.x, w1, a1[4]);
      a0[5] = fmaf(f1.y, w0, a0[5]);  a1[5] = fmaf(f1.y, w1, a1[5]);
      a0[6] = fmaf(f1.z, w0, a0[6]);  a1[6] = fmaf(f1.z, w1, a1[6]);
      a0[7] = fmaf(f1.w, w0, a0[7]);  a1[7] = fmaf(f1.w, w1, a1[7]);
    }
    float* d0 = &h2T[j0][kh * 8];
    float* d1 = &h2T[j0 + 64][kh * 8];
    #pragma unroll
    for (int r = 0; r < 8; ++r) { d0[r] = fmaxf(a0[r], 0.0f); d1[r] = fmaxf(a1[r], 0.0f); }
  }
  __syncthreads();

  // layer 3 + max-pool: outputs (j0, j0+128), 16 points each. kh = t>>7.
  {
    const int j0 = t & 127, kh = t >> 7;
    float a0[16], a1[16];
    float bb0 = b3[j0], bb1 = b3[j0 + 128];
    #pragma unroll
    for (int r = 0; r < 16; ++r) { a0[r] = bb0; a1[r] = bb1; }
    for (int c = 0; c < 128; ++c) {
      float w0 = W3[c * 256 + j0];
      float w1 = W3[c * 256 + j0 + 128];
      const float4* hp = (const float4*)&h2T[c][kh * 16];
      #pragma unroll
      for (int q = 0; q < 4; ++q) {
        float4 f = hp[q];
        a0[q*4+0] = fmaf(f.x, w0, a0[q*4+0]);  a1[q*4+0] = fmaf(f.x, w1, a1[q*4+0]);
        a0[q*4+1] = fmaf(f.y, w0, a0[q*4+1]);  a1[q*4+1] = fmaf(f.y, w1, a1[q*4+1]);
        a0[q*4+2] = fmaf(f.z, w0, a0[q*4+2]);  a1[q*4+2] = fmaf(f.z, w1, a1[q*4+2]);
        a0[q*4+3] = fmaf(f.w, w0, a0[q*4+3]);  a1[q*4+3] = fmaf(f.w, w1, a1[q*4+3]);
      }
    }
    float m0 = a0[0], m1 = a1[0];
    #pragma unroll
    for (int r = 1; r < 16; ++r) { m0 = fmaxf(m0, a0[r]); m1 = fmaxf(m1, a1[r]); }
    pmax[kh][j0]       = m0;
    pmax[kh][j0 + 128] = m1;
  }
  __syncthreads();

  {
    float v = fmaxf(pmax[0][t], pmax[1][t]);
    out[(size_t)bs * 256 + t] = fmaxf(v, 0.0f);   // relu(max) == max(relu)
  }
}

// ---------------------------------------------------------------------------
extern "C" void kernel_launch(void* const* d_in, const int* in_sizes, int n_in,
                              void* d_out, int out_size, void* d_ws, size_t ws_size,
                              hipStream_t stream) {
  const float* xyz = (const float*)d_in[0];
  const float* fea = (const float*)d_in[1];
  const float* W1  = (const float*)d_in[2];
  const float* b1  = (const float*)d_in[3];
  const float* W2  = (const float*)d_in[4];
  const float* b2  = (const float*)d_in[5];
  const float* W3  = (const float*)d_in[6];
  const float* b3  = (const float*)d_in[7];

  float* outp    = (float*)d_out;
  float* sampled = outp;                    // output 0: (16,1024,3)
  float* mlp_out = outp + 16 * 1024 * 3;    // output 1: (16,1024,256)
  int*   gidx    = (int*)d_ws;              // 16384*32 ints = 2 MB scratch

  fps_kernel<<<16, 512, 0, stream>>>(xyz, sampled);
  ball_kernel<<<4096, 256, 0, stream>>>(xyz, sampled, gidx);
  mlp_kernel<<<16384, 256, 0, stream>>>(xyz, fea, sampled, gidx,
                                        W1, b1, W2, b2, W3, b3, mlp_out);
}

// Round 11
// 1096.213 us; speedup vs baseline: 2.0233x; 1.4327x over previous
//
#include <hip/hip_runtime.h>
#include <hip/hip_bf16.h>

#define N_PTS 8192
#define NSAMP 1024
#define NGRP  32

typedef __attribute__((ext_vector_type(8))) short bf16x8;   // MFMA A/B frag
typedef __attribute__((ext_vector_type(4))) float f32x4;    // MFMA C/D frag

static __device__ inline unsigned short f2bf(float f) {
  __hip_bfloat16 h = __float2bfloat16(f);   // RTNE
  return __builtin_bit_cast(unsigned short, h);
}

// DPP max step: invalid lanes keep 'old' (=r), identity for max.
#define DPP_MAXSTEP(r, ctrl)                                                  \
  r = fmaxf(r, __int_as_float(__builtin_amdgcn_update_dpp(                    \
          __float_as_int(r), __float_as_int(r), (ctrl), 0xf, 0xf, false)))

// ---------------------------------------------------------------------------
// Kernel 1: farthest point sampling — EXACT R7 version (measured 859us floor).
// Lockstep floor model (R7-R10): issue phase (~600cy, irreducible on 1 CU) +
// serial phase (~800cy) that the barrier prevents overlapping. Do not tinker.
// Distance rounding matches XLA:CPU's scan-compiled contracted reduce:
//   d = fma(dz,dz, fma(dy,dy, dx*dx))          (bit-exact, DO NOT TOUCH)
// argmax ties -> lowest index.
// ---------------------------------------------------------------------------
__global__
__attribute__((amdgpu_flat_work_group_size(512, 512)))
__attribute__((amdgpu_waves_per_eu(2, 2)))
void fps_kernel(
    const float* __restrict__ xyz, float* __restrict__ out_sampled)
{
  #pragma clang fp contract(off)
  const int b = blockIdx.x;
  const int t = threadIdx.x;
  const float* bx = xyz + (size_t)b * N_PTS * 3;

  float px[16], py[16], pz[16], dist[16];
  {
    const float4* src = (const float4*)(bx + t * 48);
    float4 v0 = src[0], v1 = src[1], v2 = src[2];
    float4 v3 = src[3], v4 = src[4], v5 = src[5];
    float4 v6 = src[6], v7 = src[7], v8 = src[8];
    float4 v9 = src[9], v10 = src[10], v11 = src[11];
    px[ 0]=v0.x; py[ 0]=v0.y; pz[ 0]=v0.z;
    px[ 1]=v0.w; py[ 1]=v1.x; pz[ 1]=v1.y;
    px[ 2]=v1.z; py[ 2]=v1.w; pz[ 2]=v2.x;
    px[ 3]=v2.y; py[ 3]=v2.z; pz[ 3]=v2.w;
    px[ 4]=v3.x; py[ 4]=v3.y; pz[ 4]=v3.z;
    px[ 5]=v3.w; py[ 5]=v4.x; pz[ 5]=v4.y;
    px[ 6]=v4.z; py[ 6]=v4.w; pz[ 6]=v5.x;
    px[ 7]=v5.y; py[ 7]=v5.z; pz[ 7]=v5.w;
    px[ 8]=v6.x; py[ 8]=v6.y; pz[ 8]=v6.z;
    px[ 9]=v6.w; py[ 9]=v7.x; pz[ 9]=v7.y;
    px[10]=v7.z; py[10]=v7.w; pz[10]=v8.x;
    px[11]=v8.y; py[11]=v8.z; pz[11]=v8.w;
    px[12]=v9.x; py[12]=v9.y; pz[12]=v9.z;
    px[13]=v9.w; py[13]=v10.x; pz[13]=v10.y;
    px[14]=v10.z; py[14]=v10.w; pz[14]=v11.x;
    px[15]=v11.y; py[15]=v11.z; pz[15]=v11.w;
  }
  #pragma unroll
  for (int r = 0; r < 16; ++r) dist[r] = 10000000000.0f;

  __shared__ uint2 part[2][8];          // ping-pong (value bits, index)
  __shared__ float out_lds[NSAMP * 3];  // centroids, flushed at end

  const int lane = t & 63;
  const int wv   = t >> 6;

  float cx = bx[0], cy = bx[1], cz = bx[2];  // initial centroid = point 0

  for (int it = 0; it < NSAMP; ++it) {
    if (t == 0) {
      out_lds[it * 3 + 0] = cx;
      out_lds[it * 3 + 1] = cy;
      out_lds[it * 3 + 2] = cz;
    }

    float bv = -1.0f;
    #pragma unroll
    for (int r = 0; r < 16; ++r) {
      float dx = px[r] - cx;
      float dy = py[r] - cy;
      float dz = pz[r] - cz;
      float d  = fmaf(dz, dz, fmaf(dy, dy, dx * dx));  // scan-fused rounding
      float nd = fminf(dist[r], d);
      dist[r] = nd;
      bv = fmaxf(bv, nd);
    }
    int bi = t * 16 + 15;
    #pragma unroll
    for (int r = 14; r >= 0; --r) bi = (dist[r] == bv) ? (t * 16 + r) : bi;

    float rmax = bv;
    DPP_MAXSTEP(rmax, 0x111);  // row_shr:1
    DPP_MAXSTEP(rmax, 0x112);  // row_shr:2
    DPP_MAXSTEP(rmax, 0x114);  // row_shr:4
    DPP_MAXSTEP(rmax, 0x118);  // row_shr:8
    DPP_MAXSTEP(rmax, 0x142);  // row_bcast:15
    DPP_MAXSTEP(rmax, 0x143);  // row_bcast:31
    float vmax = __int_as_float(
        __builtin_amdgcn_readlane(__float_as_int(rmax), 63));

    unsigned long long m = __ballot(bv == vmax);
    int L = __ffsll((long long)m) - 1;
    int widx = __builtin_amdgcn_readlane(bi, L);

    const int slot = it & 1;
    if (lane == 0) part[slot][wv] = make_uint2(__float_as_uint(vmax), (unsigned)widx);
    __syncthreads();   // the ONLY barrier; ping-pong makes it WAR-safe

    const uint4* pp = (const uint4*)&part[slot][0];
    uint4 p0 = pp[0], p1 = pp[1], p2 = pp[2], p3 = pp[3];
    float v = __uint_as_float(p0.x); unsigned f = p0.y;
    float w1v = __uint_as_float(p0.z);
    if (w1v > v) { v = w1v; f = p0.w; }
    float w2v = __uint_as_float(p1.x);
    if (w2v > v) { v = w2v; f = p1.y; }
    float w3v = __uint_as_float(p1.z);
    if (w3v > v) { v = w3v; f = p1.w; }
    float w4v = __uint_as_float(p2.x);
    if (w4v > v) { v = w4v; f = p2.y; }
    float w5v = __uint_as_float(p2.z);
    if (w5v > v) { v = w5v; f = p2.w; }
    float w6v = __uint_as_float(p3.x);
    if (w6v > v) { v = w6v; f = p3.y; }
    float w7v = __uint_as_float(p3.z);
    if (w7v > v) { v = w7v; f = p3.w; }

    cx = bx[f * 3 + 0];
    cy = bx[f * 3 + 1];
    cz = bx[f * 3 + 2];
  }

  __syncthreads();
  float* ob = out_sampled + (size_t)b * NSAMP * 3;
  for (int i = t; i < NSAMP * 3; i += 512) ob[i] = out_lds[i];
}

// ---------------------------------------------------------------------------
// Kernel 2: query_ball_point — unchanged (bit-exact, DO NOT TOUCH).
// ---------------------------------------------------------------------------
__global__ __launch_bounds__(256) void ball_kernel(
    const float* __restrict__ xyz, const float* __restrict__ sampled,
    int* __restrict__ gidx)
{
  #pragma clang fp contract(off)
  const float R2 = (float)(0.2 * 0.2);
  int gt = blockIdx.x * 256 + threadIdx.x;
  int w = gt >> 6;
  int lane = gt & 63;
  const int b = w >> 10;
  const float* cp = sampled + (size_t)w * 3;
  float cx = cp[0], cy = cp[1], cz = cp[2];
  float na = ((cx * cx) + (cy * cy)) + (cz * cz);   // eager: plain adds
  const float* bx = xyz + (size_t)b * N_PTS * 3;
  int* out = gidx + (size_t)w * NGRP;

  int cnt = 0;
  int first = 0;
  for (int base = 0; base < N_PTS && cnt < NGRP; base += 64) {
    int p = base + lane;
    float x = bx[p * 3 + 0];
    float y = bx[p * 3 + 1];
    float z = bx[p * 3 + 2];
    float nb  = ((x * x) + (y * y)) + (z * z);      // eager: plain adds
    float dot = fmaf(cz, z, fmaf(cy, y, cx * x));   // Eigen fma chain
    float sq  = (na + nb) - (2.0f * dot);
    bool inr = !(sq > R2);
    unsigned long long m = __ballot(inr);
    if (cnt == 0 && m != 0ull) first = base + (__ffsll(m) - 1);
    int before = __popcll(m & ((1ull << lane) - 1ull));
    int pos = cnt + before;
    if (inr && pos < NGRP) out[pos] = p;
    cnt += __popcll(m);
  }
  if (cnt < NGRP) {
    int q = cnt + lane;
    if (q < NGRP) out[q] = first;
  }
}

// ---------------------------------------------------------------------------
// Kernel 2.5: weight prep — pack W1/W2/W3 into fragment-ordered bf16 records.
// Record (nt, ks) holds the B-fragment for one 16-col tile / one K-step:
//   record[lane][j] = W[k = 32ks + (lane>>4)*8 + j][n = 16nt + (lane&15)]
// (zero-padded k >= K). 1KB/record, lane*16B consecutive -> coalesced loads.
// Layers: L1 4nt x 3ks = 12 recs, L2 8x2 = 16, L3 16x4 = 64. Total 92KB.
// ---------------------------------------------------------------------------
__global__ __launch_bounds__(256) void prep_w_kernel(
    const float* __restrict__ W1, const float* __restrict__ W2,
    const float* __restrict__ W3, unsigned short* __restrict__ wf1,
    unsigned short* __restrict__ wf2, unsigned short* __restrict__ wf3)
{
  int tid = blockIdx.x * 256 + threadIdx.x;
  int rec = tid >> 6, lane = tid & 63;
  if (rec >= 92) return;
  const float* W; unsigned short* dst; int N, K, ksteps, rl;
  if (rec < 12)      { W = W1; dst = wf1; N = 64;  K = 67;  ksteps = 3; rl = rec; }
  else if (rec < 28) { W = W2; dst = wf2; N = 128; K = 64;  ksteps = 2; rl = rec - 12; }
  else               { W = W3; dst = wf3; N = 256; K = 128; ksteps = 4; rl = rec - 28; }
  int nt = rl / ksteps, ks = rl - nt * ksteps;
  int n  = nt * 16 + (lane & 15);
  int kb = ks * 32 + (lane >> 4) * 8;
  unsigned short v[8] __attribute__((aligned(16)));
  #pragma unroll
  for (int j = 0; j < 8; ++j) {
    int k = kb + j;
    v[j] = f2bf((k < K) ? W[k * N + n] : 0.0f);
  }
  *(uint4*)(dst + ((size_t)rl * 64 + lane) * 8) = *(const uint4*)v;
}

// ---------------------------------------------------------------------------
// Kernel 3: gather + MLP via bf16 MFMA (fp32 accumulate) + max-pool.
// One 256-thread block (4 waves) per centroid.
// Frag layouts (gfx950, HW-verified per guide):
//   A[m=lane&15][k=(lane>>4)*8+j]   B[n=lane&15][k=(lane>>4)*8+j]
//   C/D: col=lane&15, row=(lane>>4)*4+reg
// Activations in bf16 LDS tiles, row stride K+8 (breaks 128B bank pathology).
// B-frags load straight from fragment-ordered global records (L2-hot).
// Accuracy: bf16 operand rounding -> out err ~2-5e-3 << 2e-2 threshold.
// ---------------------------------------------------------------------------
__global__ __launch_bounds__(256, 4) void mlp_mfma_kernel(
    const float* __restrict__ xyz, const float* __restrict__ fea,
    const float* __restrict__ sampled, const int* __restrict__ gidx,
    const unsigned short* __restrict__ wf1, const unsigned short* __restrict__ wf2,
    const unsigned short* __restrict__ wf3, const float* __restrict__ b1,
    const float* __restrict__ b2, const float* __restrict__ b3,
    float* __restrict__ out)
{
  __shared__ __align__(16) unsigned short fT[32][104];  // feats bf16, K=96 pad
  __shared__ __align__(16) unsigned short h1[32][72];   // K=64 (+8 bank pad)
  __shared__ __align__(16) unsigned short h2[32][136];  // K=128 (+8 bank pad)
  __shared__ float pmax[8][256];
  __shared__ int   sidx[32];
  __shared__ float sc[4];

  const int bs = blockIdx.x;
  const int b  = bs >> 10;
  const int t  = threadIdx.x;
  const int w    = t >> 6;
  const int lane = t & 63;
  const int quad = lane >> 4;
  const int ncol = lane & 15;

  if (t < 32) sidx[t] = gidx[(size_t)bs * 32 + t];
  if (t < 3)  sc[t] = sampled[(size_t)bs * 3 + t];
  __syncthreads();

  // gather: rel(3) ++ fea(64) -> bf16 fT[pt][c], zero pad c in [67,96)
  {
    const int pt = t >> 3, c0 = t & 7;
    const int p = sidx[pt];
    const float* xp = xyz + ((size_t)b * N_PTS + p) * 3;
    const float* fp = fea + ((size_t)b * N_PTS + p) * 64;
    for (int c = c0; c < 96; c += 8) {
      float v = (c < 3) ? (xp[c] - sc[c]) : (c < 67 ? fp[c - 3] : 0.0f);
      fT[pt][c] = f2bf(v);
    }
  }
  __syncthreads();

  // layer 1: out [32 x 64]. 8 tiles (2m x 4n), 2/wave; K: 3 steps.
  #pragma unroll
  for (int q2 = 0; q2 < 2; ++q2) {
    const int tid = w * 2 + q2, mt = tid & 1, nt = tid >> 1;
    float bb = b1[nt * 16 + ncol];
    f32x4 acc = {bb, bb, bb, bb};
    #pragma unroll
    for (int ks = 0; ks < 3; ++ks) {
      bf16x8 a = *(const bf16x8*)&fT[mt * 16 + ncol][ks * 32 + quad * 8];
      bf16x8 bf = *(const bf16x8*)(wf1 + ((size_t)(nt * 3 + ks) * 64 + lane) * 8);
      acc = __builtin_amdgcn_mfma_f32_16x16x32_bf16(a, bf, acc, 0, 0, 0);
    }
    #pragma unroll
    for (int r = 0; r < 4; ++r)
      h1[mt * 16 + quad * 4 + r][nt * 16 + ncol] = f2bf(fmaxf(acc[r], 0.0f));
  }
  __syncthreads();

  // layer 2: out [32 x 128]. 16 tiles (2m x 8n), 4/wave; K: 2 steps.
  #pragma unroll
  for (int q2 = 0; q2 < 4; ++q2) {
    const int tid = w * 4 + q2, mt = tid & 1, nt = tid >> 1;
    float bb = b2[nt * 16 + ncol];
    f32x4 acc = {bb, bb, bb, bb};
    #pragma unroll
    for (int ks = 0; ks < 2; ++ks) {
      bf16x8 a = *(const bf16x8*)&h1[mt * 16 + ncol][ks * 32 + quad * 8];
      bf16x8 bf = *(const bf16x8*)(wf2 + ((size_t)(nt * 2 + ks) * 64 + lane) * 8);
      acc = __builtin_amdgcn_mfma_f32_16x16x32_bf16(a, bf, acc, 0, 0, 0);
    }
    #pragma unroll
    for (int r = 0; r < 4; ++r)
      h2[mt * 16 + quad * 4 + r][nt * 16 + ncol] = f2bf(fmaxf(acc[r], 0.0f));
  }
  __syncthreads();

  // layer 3 + pool: out [32 x 256]. 32 tiles (2m x 16n), 8/wave; K: 4 steps.
  #pragma unroll
  for (int q2 = 0; q2 < 8; ++q2) {
    const int tid = w * 8 + q2, mt = tid & 1, nt = tid >> 1;
    float bb = b3[nt * 16 + ncol];
    f32x4 acc = {bb, bb, bb, bb};
    #pragma unroll
    for (int ks = 0; ks < 4; ++ks) {
      bf16x8 a = *(const bf16x8*)&h2[mt * 16 + ncol][ks * 32 + quad * 8];
      bf16x8 bf = *(const bf16x8*)(wf3 + ((size_t)(nt * 4 + ks) * 64 + lane) * 8);
      acc = __builtin_amdgcn_mfma_f32_16x16x32_bf16(a, bf, acc, 0, 0, 0);
    }
    float mx = fmaxf(fmaxf(acc[0], acc[1]), fmaxf(acc[2], acc[3]));
    pmax[mt * 4 + quad][nt * 16 + ncol] = mx;   // partial over 4 rows
  }
  __syncthreads();

  {
    float v = pmax[0][t];
    #pragma unroll
    for (int s = 1; s < 8; ++s) v = fmaxf(v, pmax[s][t]);
    out[(size_t)bs * 256 + t] = fmaxf(v, 0.0f);   // relu(max) == max(relu)
  }
}

// ---------------------------------------------------------------------------
extern "C" void kernel_launch(void* const* d_in, const int* in_sizes, int n_in,
                              void* d_out, int out_size, void* d_ws, size_t ws_size,
                              hipStream_t stream) {
  const float* xyz = (const float*)d_in[0];
  const float* fea = (const float*)d_in[1];
  const float* W1  = (const float*)d_in[2];
  const float* b1  = (const float*)d_in[3];
  const float* W2  = (const float*)d_in[4];
  const float* b2  = (const float*)d_in[5];
  const float* W3  = (const float*)d_in[6];
  const float* b3  = (const float*)d_in[7];

  float* outp    = (float*)d_out;
  float* sampled = outp;                    // output 0: (16,1024,3)
  float* mlp_out = outp + 16 * 1024 * 3;    // output 1: (16,1024,256)
  int*   gidx    = (int*)d_ws;              // 2 MB
  unsigned short* wf1 = (unsigned short*)((char*)d_ws + (2u << 20));
  unsigned short* wf2 = wf1 + (size_t)12 * 64 * 8;   // 12 KB after wf1
  unsigned short* wf3 = wf2 + (size_t)16 * 64 * 8;   // 16 KB after wf2

  fps_kernel<<<16, 512, 0, stream>>>(xyz, sampled);
  prep_w_kernel<<<23, 256, 0, stream>>>(W1, W2, W3, wf1, wf2, wf3);
  ball_kernel<<<4096, 256, 0, stream>>>(xyz, sampled, gidx);
  mlp_mfma_kernel<<<16384, 256, 0, stream>>>(xyz, fea, sampled, gidx,
                                             wf1, wf2, wf3, b1, b2, b3, mlp_out);
}